// Round 1
// baseline (2485.244 us; speedup 1.0000x reference)
//
#include <hip/hip_runtime.h>

// Problem constants (from reference)
constexpr int N_NODES  = 100000;
constexpr int N_EDGES  = 1200000;
constexpr int N_GRAPHS = 1000;
constexpr int DIM      = 64;   // IN_DIM == MSG_DIM == HID_DIM
constexpr int ODIM     = 32;   // OUT_DIM
constexpr int MAXD     = 10;

// ---------------------------------------------------------------------------
// Scatter: hsum[dst] += xin[src] over all edges (64-dim), optionally count deg
// thread = edge*16 + quad ; each thread handles 4 contiguous dims via float4
// ---------------------------------------------------------------------------
__global__ void scatter_add_kernel(const float* __restrict__ xin,
                                   const int* __restrict__ src,
                                   const int* __restrict__ dst,
                                   float* __restrict__ hsum,
                                   int* __restrict__ deg,
                                   int count_deg) {
    long long tid = (long long)blockIdx.x * blockDim.x + threadIdx.x;
    if (tid >= (long long)N_EDGES * 16) return;
    int e = (int)(tid >> 4);
    int q = (int)(tid & 15);
    int s = src[e];
    int t = dst[e];
    const float4 v = *reinterpret_cast<const float4*>(xin + (long long)s * DIM + q * 4);
    float* base = hsum + (long long)t * DIM + q * 4;
    atomicAdd(base + 0, v.x);
    atomicAdd(base + 1, v.y);
    atomicAdd(base + 2, v.z);
    atomicAdd(base + 3, v.w);
    if (count_deg && q == 0) atomicAdd(&deg[t], 1);
}

// ---------------------------------------------------------------------------
// MFConv apply: one wave (64 lanes) per node; lane = output dim.
//   out[n][o] = sum_i hsum[n][i]*Wl[d][i][o] + bl[d][o] + sum_i xin[n][i]*Wr[d][i][o]
// optionally relu. 4 waves / 256-thread block.
// ---------------------------------------------------------------------------
__global__ void conv_kernel(const float* __restrict__ hsum,
                            const float* __restrict__ xin,
                            const int* __restrict__ deg,
                            const float* __restrict__ Wl,
                            const float* __restrict__ bl,
                            const float* __restrict__ Wr,
                            float* __restrict__ out,
                            int do_relu) {
    int node = blockIdx.x * (blockDim.x >> 6) + (threadIdx.x >> 6);
    int lane = threadIdx.x & 63;
    if (node >= N_NODES) return;
    int d = deg[node];
    d = d > MAXD ? MAXD : d;
    const float* wl = Wl + (long long)d * DIM * DIM;
    const float* wr = Wr + (long long)d * DIM * DIM;
    const float* hs = hsum + (long long)node * DIM;
    const float* xv = xin + (long long)node * DIM;
    float acc = bl[d * DIM + lane];
#pragma unroll 8
    for (int i = 0; i < DIM; ++i) {
        acc += hs[i] * wl[i * DIM + lane] + xv[i] * wr[i * DIM + lane];
    }
    if (do_relu) acc = fmaxf(acc, 0.0f);
    out[(long long)node * DIM + lane] = acc;
}

// ---------------------------------------------------------------------------
// MFConv #2 apply + emb write + relu-pool into per-graph accumulator
// ---------------------------------------------------------------------------
__global__ void conv2_kernel(const float* __restrict__ hsum,
                             const float* __restrict__ xin,
                             const int* __restrict__ deg,
                             const float* __restrict__ Wl,
                             const float* __restrict__ bl,
                             const float* __restrict__ Wr,
                             const int* __restrict__ batch,
                             float* __restrict__ emb,
                             float* __restrict__ g) {
    int node = blockIdx.x * (blockDim.x >> 6) + (threadIdx.x >> 6);
    int lane = threadIdx.x & 63;
    if (node >= N_NODES) return;
    int d = deg[node];
    d = d > MAXD ? MAXD : d;
    const float* wl = Wl + (long long)d * DIM * DIM;
    const float* wr = Wr + (long long)d * DIM * DIM;
    const float* hs = hsum + (long long)node * DIM;
    const float* xv = xin + (long long)node * DIM;
    float acc = bl[d * DIM + lane];
#pragma unroll 8
    for (int i = 0; i < DIM; ++i) {
        acc += hs[i] * wl[i * DIM + lane] + xv[i] * wr[i * DIM + lane];
    }
    emb[(long long)node * DIM + lane] = acc;
    float r = fmaxf(acc, 0.0f);
    atomicAdd(&g[(long long)batch[node] * DIM + lane], r);
}

// ---------------------------------------------------------------------------
// Head: per graph, hid = g@W1 + b1 ; pred = hid@W2 + b2
// one 64-thread block per graph
// ---------------------------------------------------------------------------
__global__ void head_kernel(const float* __restrict__ g,
                            const float* __restrict__ W1,
                            const float* __restrict__ b1,
                            const float* __restrict__ W2,
                            const float* __restrict__ b2,
                            float* __restrict__ pred) {
    __shared__ float hid[DIM];
    int gi = blockIdx.x;
    int o = threadIdx.x;
    const float* gv = g + (long long)gi * DIM;
    float acc = b1[o];
#pragma unroll 8
    for (int i = 0; i < DIM; ++i) acc += gv[i] * W1[i * DIM + o];
    hid[o] = acc;
    __syncthreads();
    if (o < ODIM) {
        float p = b2[o];
#pragma unroll 8
        for (int i = 0; i < DIM; ++i) p += hid[i] * W2[i * ODIM + o];
        pred[(long long)gi * ODIM + o] = p;
    }
}

extern "C" void kernel_launch(void* const* d_in, const int* in_sizes, int n_in,
                              void* d_out, int out_size, void* d_ws, size_t ws_size,
                              hipStream_t stream) {
    const float* x    = (const float*)d_in[0];
    const int* eidx   = (const int*)d_in[1];
    const int* src    = eidx;
    const int* dst    = eidx + N_EDGES;
    const int* batch  = (const int*)d_in[2];
    const float* Wl1  = (const float*)d_in[4];
    const float* bl1  = (const float*)d_in[5];
    const float* Wr1  = (const float*)d_in[6];
    const float* Wl2  = (const float*)d_in[7];
    const float* bl2  = (const float*)d_in[8];
    const float* Wr2  = (const float*)d_in[9];
    const float* W1   = (const float*)d_in[10];
    const float* b1   = (const float*)d_in[11];
    const float* W2   = (const float*)d_in[12];
    const float* b2   = (const float*)d_in[13];

    float* emb  = (float*)d_out;                      // [N_NODES, 64]
    float* pred = (float*)d_out + (size_t)N_NODES * DIM;  // [N_GRAPHS, 32]

    // Workspace layout
    float* hsum  = (float*)d_ws;                       // [N,64]
    float* hrelu = hsum + (size_t)N_NODES * DIM;       // [N,64]
    int*   deg   = (int*)(hrelu + (size_t)N_NODES * DIM); // [N]
    float* g     = (float*)(deg + N_NODES);            // [N_GRAPHS,64]

    // Zero accumulators (fresh every call — harness does not re-poison)
    hipMemsetAsync(hsum, 0, (size_t)N_NODES * DIM * sizeof(float), stream);
    hipMemsetAsync(deg, 0, (size_t)N_NODES * sizeof(int), stream);
    hipMemsetAsync(g, 0, (size_t)N_GRAPHS * DIM * sizeof(float), stream);

    // conv1 scatter: hsum = segment_sum(x[src], dst), deg = in-degree
    {
        long long total = (long long)N_EDGES * 16;
        int blocks = (int)((total + 255) / 256);
        scatter_add_kernel<<<blocks, 256, 0, stream>>>(x, src, dst, hsum, deg, 1);
    }
    // conv1 apply + relu
    {
        int blocks = (N_NODES + 3) / 4;
        conv_kernel<<<blocks, 256, 0, stream>>>(hsum, x, deg, Wl1, bl1, Wr1, hrelu, 1);
    }
    // reset hsum for conv2
    hipMemsetAsync(hsum, 0, (size_t)N_NODES * DIM * sizeof(float), stream);
    // conv2 scatter
    {
        long long total = (long long)N_EDGES * 16;
        int blocks = (int)((total + 255) / 256);
        scatter_add_kernel<<<blocks, 256, 0, stream>>>(hrelu, src, dst, hsum, deg, 0);
    }
    // conv2 apply -> emb (no relu) + relu-pool into g
    {
        int blocks = (N_NODES + 3) / 4;
        conv2_kernel<<<blocks, 256, 0, stream>>>(hsum, hrelu, deg, Wl2, bl2, Wr2,
                                                 batch, emb, g);
    }
    // head
    head_kernel<<<N_GRAPHS, DIM, 0, stream>>>(g, W1, b1, W2, b2, pred);
}

// Round 2
// 690.306 us; speedup vs baseline: 3.6002x; 3.6002x over previous
//
#include <hip/hip_runtime.h>

constexpr int N_NODES  = 100000;
constexpr int N_EDGES  = 1200000;
constexpr int N_GRAPHS = 1000;
constexpr int DIM      = 64;
constexpr int ODIM     = 32;
constexpr int MAXD     = 10;

// ---------------------------------------------------------------------------
// CSR build step 1: in-degree histogram (int atomics, cheap)
// ---------------------------------------------------------------------------
__global__ void deg_hist_kernel(const int* __restrict__ dst, int* __restrict__ deg) {
    int e = blockIdx.x * blockDim.x + threadIdx.x;
    if (e < N_EDGES) atomicAdd(&deg[dst[e]], 1);
}

// ---------------------------------------------------------------------------
// CSR build step 2: exclusive scan deg[n] -> rowptr[n+1]; single 1024-thread block
// ---------------------------------------------------------------------------
__global__ void scan_kernel(const int* __restrict__ deg, int* __restrict__ rowptr, int n) {
    __shared__ int part[1024];
    int t = threadIdx.x;
    int chunk = (n + 1023) / 1024;
    int beg = t * chunk;
    int end = min(beg + chunk, n);
    int s = 0;
    for (int i = beg; i < end; ++i) s += deg[i];
    part[t] = s;
    __syncthreads();
    for (int off = 1; off < 1024; off <<= 1) {
        int v = (t >= off) ? part[t - off] : 0;
        __syncthreads();
        part[t] += v;
        __syncthreads();
    }
    int run = part[t] - s;  // exclusive prefix
    for (int i = beg; i < end; ++i) { rowptr[i] = run; run += deg[i]; }
    if (t == 1023) rowptr[n] = part[1023];
}

__global__ void init_cursor_kernel(const int* __restrict__ rowptr, int* __restrict__ cursor) {
    int i = blockIdx.x * blockDim.x + threadIdx.x;
    if (i < N_NODES) cursor[i] = rowptr[i];
}

// ---------------------------------------------------------------------------
// CSR build step 3: bin edges; csr[pos] = src node id
// ---------------------------------------------------------------------------
__global__ void fill_csr_kernel(const int* __restrict__ src, const int* __restrict__ dst,
                                int* __restrict__ cursor, int* __restrict__ csr) {
    int e = blockIdx.x * blockDim.x + threadIdx.x;
    if (e < N_EDGES) {
        int p = atomicAdd(&cursor[dst[e]], 1);
        csr[p] = src[e];
    }
}

// ---------------------------------------------------------------------------
// Graph node ranges via binary search on sorted batch (no atomics)
// ---------------------------------------------------------------------------
__global__ void graph_bounds_kernel(const int* __restrict__ batch, int* __restrict__ grow) {
    int t = blockIdx.x * blockDim.x + threadIdx.x;
    if (t > N_GRAPHS) return;
    if (t == N_GRAPHS) { grow[t] = N_NODES; return; }
    int lo = 0, hi = N_NODES;
    while (lo < hi) { int mid = (lo + hi) >> 1; if (batch[mid] < t) lo = mid + 1; else hi = mid; }
    grow[t] = lo;
}

// ---------------------------------------------------------------------------
// Fused gather + MFConv: one wave per node, lane = output dim.
// hsum gathered in registers (lane i holds dim i), staged to LDS for the matvec.
// ---------------------------------------------------------------------------
template <int RELU>
__global__ void gather_conv_kernel(const float* __restrict__ xin,
                                   const int* __restrict__ rowptr,
                                   const int* __restrict__ csr,
                                   const float* __restrict__ Wl,
                                   const float* __restrict__ bl,
                                   const float* __restrict__ Wr,
                                   float* __restrict__ out) {
    __shared__ float sh[4][2][DIM];  // [wave][hs|xv][dim]
    int w = threadIdx.x >> 6;
    int lane = threadIdx.x & 63;
    int node = blockIdx.x * 4 + w;   // grid = N/4 exactly (100000 % 4 == 0)

    int beg = rowptr[node];
    int end = rowptr[node + 1];
    float hs = 0.f;
    for (int e = beg; e < end; ++e) {
        int s = csr[e];                      // uniform across wave -> broadcast
        hs += xin[(size_t)s * DIM + lane];   // coalesced 256B, L2/L3 hit
    }
    sh[w][0][lane] = hs;
    sh[w][1][lane] = xin[(size_t)node * DIM + lane];
    __syncthreads();

    int d = end - beg;
    d = d > MAXD ? MAXD : d;
    const float* wl = Wl + (size_t)d * DIM * DIM;
    const float* wr = Wr + (size_t)d * DIM * DIM;
    float acc = bl[d * DIM + lane];
#pragma unroll 8
    for (int i = 0; i < DIM; ++i) {
        acc += sh[w][0][i] * wl[i * DIM + lane] + sh[w][1][i] * wr[i * DIM + lane];
    }
    if (RELU) acc = fmaxf(acc, 0.f);
    out[(size_t)node * DIM + lane] = acc;
}

// ---------------------------------------------------------------------------
// global_add_pool of relu(emb): one block per graph, contiguous node range
// ---------------------------------------------------------------------------
__global__ void pool_kernel(const float* __restrict__ emb,
                            const int* __restrict__ grow,
                            float* __restrict__ g) {
    __shared__ float red[4][DIM];
    int gi = blockIdx.x;
    int w = threadIdx.x >> 6;
    int lane = threadIdx.x & 63;
    int beg = grow[gi], end = grow[gi + 1];
    float acc = 0.f;
    for (int n = beg + w; n < end; n += 4)
        acc += fmaxf(emb[(size_t)n * DIM + lane], 0.f);
    red[w][lane] = acc;
    __syncthreads();
    if (w == 0) {
        g[(size_t)gi * DIM + lane] = red[0][lane] + red[1][lane] + red[2][lane] + red[3][lane];
    }
}

// ---------------------------------------------------------------------------
// Head: hid = g@W1 + b1 ; pred = hid@W2 + b2 (one 64-thread block per graph)
// ---------------------------------------------------------------------------
__global__ void head_kernel(const float* __restrict__ g,
                            const float* __restrict__ W1,
                            const float* __restrict__ b1,
                            const float* __restrict__ W2,
                            const float* __restrict__ b2,
                            float* __restrict__ pred) {
    __shared__ float hid[DIM];
    int gi = blockIdx.x;
    int o = threadIdx.x;
    const float* gv = g + (size_t)gi * DIM;
    float acc = b1[o];
#pragma unroll 8
    for (int i = 0; i < DIM; ++i) acc += gv[i] * W1[i * DIM + o];
    hid[o] = acc;
    __syncthreads();
    if (o < ODIM) {
        float p = b2[o];
#pragma unroll 8
        for (int i = 0; i < DIM; ++i) p += hid[i] * W2[i * ODIM + o];
        pred[(size_t)gi * ODIM + o] = p;
    }
}

extern "C" void kernel_launch(void* const* d_in, const int* in_sizes, int n_in,
                              void* d_out, int out_size, void* d_ws, size_t ws_size,
                              hipStream_t stream) {
    const float* x    = (const float*)d_in[0];
    const int* eidx   = (const int*)d_in[1];
    const int* src    = eidx;
    const int* dst    = eidx + N_EDGES;
    const int* batch  = (const int*)d_in[2];
    const float* Wl1  = (const float*)d_in[4];
    const float* bl1  = (const float*)d_in[5];
    const float* Wr1  = (const float*)d_in[6];
    const float* Wl2  = (const float*)d_in[7];
    const float* bl2  = (const float*)d_in[8];
    const float* Wr2  = (const float*)d_in[9];
    const float* W1   = (const float*)d_in[10];
    const float* b1   = (const float*)d_in[11];
    const float* W2   = (const float*)d_in[12];
    const float* b2   = (const float*)d_in[13];

    float* emb  = (float*)d_out;                          // [N_NODES, 64]
    float* pred = (float*)d_out + (size_t)N_NODES * DIM;  // [N_GRAPHS, 32]

    // Workspace layout (ints first, then floats)
    int*   deg    = (int*)d_ws;                 // [N]
    int*   rowptr = deg + N_NODES;              // [N+1]
    int*   cursor = rowptr + N_NODES + 1;       // [N]
    int*   csr    = cursor + N_NODES;           // [E]
    int*   grow   = csr + N_EDGES;              // [G+1]
    float* hrelu  = (float*)(grow + N_GRAPHS + 1);       // [N,64]
    float* g      = hrelu + (size_t)N_NODES * DIM;       // [G,64]

    hipMemsetAsync(deg, 0, (size_t)N_NODES * sizeof(int), stream);

    // CSR build (shared by both convs)
    deg_hist_kernel<<<(N_EDGES + 255) / 256, 256, 0, stream>>>(dst, deg);
    scan_kernel<<<1, 1024, 0, stream>>>(deg, rowptr, N_NODES);
    init_cursor_kernel<<<(N_NODES + 255) / 256, 256, 0, stream>>>(rowptr, cursor);
    fill_csr_kernel<<<(N_EDGES + 255) / 256, 256, 0, stream>>>(src, dst, cursor, csr);
    graph_bounds_kernel<<<(N_GRAPHS + 1 + 255) / 256, 256, 0, stream>>>(batch, grow);

    // conv1: gather + matvec + relu -> hrelu
    gather_conv_kernel<1><<<N_NODES / 4, 256, 0, stream>>>(x, rowptr, csr, Wl1, bl1, Wr1, hrelu);
    // conv2: gather + matvec -> emb (pre-activation output)
    gather_conv_kernel<0><<<N_NODES / 4, 256, 0, stream>>>(hrelu, rowptr, csr, Wl2, bl2, Wr2, emb);
    // pool relu(emb) per graph
    pool_kernel<<<N_GRAPHS, 256, 0, stream>>>(emb, grow, g);
    // head
    head_kernel<<<N_GRAPHS, DIM, 0, stream>>>(g, W1, b1, W2, b2, pred);
}

// Round 3
// 616.222 us; speedup vs baseline: 4.0330x; 1.1202x over previous
//
#include <hip/hip_runtime.h>

constexpr int N_NODES  = 100000;
constexpr int N_EDGES  = 1200000;
constexpr int N_GRAPHS = 1000;
constexpr int DIM      = 64;
constexpr int ODIM     = 32;
constexpr int MAXD     = 10;

// ---------------------------------------------------------------------------
// CSR build step 1: in-degree histogram
// ---------------------------------------------------------------------------
__global__ void deg_hist_kernel(const int* __restrict__ dst, int* __restrict__ deg) {
    int e = blockIdx.x * blockDim.x + threadIdx.x;
    if (e < N_EDGES) atomicAdd(&deg[dst[e]], 1);
}

// ---------------------------------------------------------------------------
// CSR build step 2: exclusive scan deg -> rowptr AND cursor; one 1024-thr block
// ---------------------------------------------------------------------------
__global__ void scan_kernel(const int* __restrict__ deg, int* __restrict__ rowptr,
                            int* __restrict__ cursor, int n) {
    __shared__ int part[1024];
    int t = threadIdx.x;
    int chunk = (n + 1023) / 1024;
    int beg = t * chunk;
    int end = min(beg + chunk, n);
    int s = 0;
    for (int i = beg; i < end; ++i) s += deg[i];
    part[t] = s;
    __syncthreads();
    for (int off = 1; off < 1024; off <<= 1) {
        int v = (t >= off) ? part[t - off] : 0;
        __syncthreads();
        part[t] += v;
        __syncthreads();
    }
    int run = part[t] - s;  // exclusive prefix
    for (int i = beg; i < end; ++i) {
        rowptr[i] = run;
        cursor[i] = run;
        run += deg[i];
    }
    if (t == 1023) rowptr[n] = part[1023];
}

// ---------------------------------------------------------------------------
// CSR build step 3: bin edges; csr[pos] = src node id
// ---------------------------------------------------------------------------
__global__ void fill_csr_kernel(const int* __restrict__ src, const int* __restrict__ dst,
                                int* __restrict__ cursor, int* __restrict__ csr) {
    int e = blockIdx.x * blockDim.x + threadIdx.x;
    if (e < N_EDGES) {
        int p = atomicAdd(&cursor[dst[e]], 1);
        csr[p] = src[e];
    }
}

// ---------------------------------------------------------------------------
// Graph node ranges via binary search on sorted batch
// ---------------------------------------------------------------------------
__global__ void graph_bounds_kernel(const int* __restrict__ batch, int* __restrict__ grow) {
    int t = blockIdx.x * blockDim.x + threadIdx.x;
    if (t > N_GRAPHS) return;
    if (t == N_GRAPHS) { grow[t] = N_NODES; return; }
    int lo = 0, hi = N_NODES;
    while (lo < hi) { int mid = (lo + hi) >> 1; if (batch[mid] < t) lo = mid + 1; else hi = mid; }
    grow[t] = lo;
}

// ---------------------------------------------------------------------------
// Fused gather + MFConv, 16 lanes per node (float4 per lane), 4 nodes/wave.
// Block = 256 threads = 16 node-groups.
//   group gather: hs4 += x[csr[e]] (16 lanes x float4, 4-edge unroll -> ILP)
//   matvec: lane q computes out dims 4q..4q+3; weights read as float4;
//           hs[i]/xv[i] broadcast from LDS.
// ---------------------------------------------------------------------------
template <int RELU>
__global__ void conv4_kernel(const float* __restrict__ xin,
                             const int* __restrict__ rowptr,
                             const int* __restrict__ csr,
                             const float* __restrict__ Wl,
                             const float* __restrict__ bl,
                             const float* __restrict__ Wr,
                             float* __restrict__ out) {
    __shared__ float lds_h[16][DIM];
    __shared__ float lds_x[16][DIM];
    int grp = threadIdx.x >> 4;   // 0..15
    int q   = threadIdx.x & 15;   // quad within node
    int node = blockIdx.x * 16 + grp;   // grid = N/16 exactly

    int beg = rowptr[node];
    int end = rowptr[node + 1];

    float4 xv = *reinterpret_cast<const float4*>(xin + (size_t)node * DIM + q * 4);
    float4 hs = make_float4(0.f, 0.f, 0.f, 0.f);

    int e = beg;
    for (; e + 4 <= end; e += 4) {
        int s0 = csr[e + 0], s1 = csr[e + 1], s2 = csr[e + 2], s3 = csr[e + 3];
        float4 a = *reinterpret_cast<const float4*>(xin + (size_t)s0 * DIM + q * 4);
        float4 b = *reinterpret_cast<const float4*>(xin + (size_t)s1 * DIM + q * 4);
        float4 c = *reinterpret_cast<const float4*>(xin + (size_t)s2 * DIM + q * 4);
        float4 d = *reinterpret_cast<const float4*>(xin + (size_t)s3 * DIM + q * 4);
        hs.x += a.x + b.x + c.x + d.x;
        hs.y += a.y + b.y + c.y + d.y;
        hs.z += a.z + b.z + c.z + d.z;
        hs.w += a.w + b.w + c.w + d.w;
    }
    for (; e < end; ++e) {
        int s = csr[e];
        float4 a = *reinterpret_cast<const float4*>(xin + (size_t)s * DIM + q * 4);
        hs.x += a.x; hs.y += a.y; hs.z += a.z; hs.w += a.w;
    }

    lds_h[grp][q * 4 + 0] = hs.x;
    lds_h[grp][q * 4 + 1] = hs.y;
    lds_h[grp][q * 4 + 2] = hs.z;
    lds_h[grp][q * 4 + 3] = hs.w;
    lds_x[grp][q * 4 + 0] = xv.x;
    lds_x[grp][q * 4 + 1] = xv.y;
    lds_x[grp][q * 4 + 2] = xv.z;
    lds_x[grp][q * 4 + 3] = xv.w;
    __syncthreads();

    int d = end - beg;
    d = d > MAXD ? MAXD : d;
    const float* wl = Wl + (size_t)d * DIM * DIM + q * 4;
    const float* wr = Wr + (size_t)d * DIM * DIM + q * 4;
    float4 acc = *reinterpret_cast<const float4*>(bl + d * DIM + q * 4);

#pragma unroll 8
    for (int i = 0; i < DIM; ++i) {
        float h  = lds_h[grp][i];
        float xx = lds_x[grp][i];
        float4 wlv = *reinterpret_cast<const float4*>(wl + i * DIM);
        float4 wrv = *reinterpret_cast<const float4*>(wr + i * DIM);
        acc.x += h * wlv.x + xx * wrv.x;
        acc.y += h * wlv.y + xx * wrv.y;
        acc.z += h * wlv.z + xx * wrv.z;
        acc.w += h * wlv.w + xx * wrv.w;
    }
    if (RELU) {
        acc.x = fmaxf(acc.x, 0.f); acc.y = fmaxf(acc.y, 0.f);
        acc.z = fmaxf(acc.z, 0.f); acc.w = fmaxf(acc.w, 0.f);
    }
    *reinterpret_cast<float4*>(out + (size_t)node * DIM + q * 4) = acc;
}

// ---------------------------------------------------------------------------
// global_add_pool of relu(emb): one block per graph, contiguous node range
// ---------------------------------------------------------------------------
__global__ void pool_kernel(const float* __restrict__ emb,
                            const int* __restrict__ grow,
                            float* __restrict__ g) {
    __shared__ float red[4][DIM];
    int gi = blockIdx.x;
    int w = threadIdx.x >> 6;
    int lane = threadIdx.x & 63;
    int beg = grow[gi], end = grow[gi + 1];
    float acc = 0.f;
    for (int n = beg + w; n < end; n += 4)
        acc += fmaxf(emb[(size_t)n * DIM + lane], 0.f);
    red[w][lane] = acc;
    __syncthreads();
    if (w == 0) {
        g[(size_t)gi * DIM + lane] = red[0][lane] + red[1][lane] + red[2][lane] + red[3][lane];
    }
}

// ---------------------------------------------------------------------------
// Head: hid = g@W1 + b1 ; pred = hid@W2 + b2 (one 64-thread block per graph)
// ---------------------------------------------------------------------------
__global__ void head_kernel(const float* __restrict__ g,
                            const float* __restrict__ W1,
                            const float* __restrict__ b1,
                            const float* __restrict__ W2,
                            const float* __restrict__ b2,
                            float* __restrict__ pred) {
    __shared__ float hid[DIM];
    int gi = blockIdx.x;
    int o = threadIdx.x;
    const float* gv = g + (size_t)gi * DIM;
    float acc = b1[o];
#pragma unroll 8
    for (int i = 0; i < DIM; ++i) acc += gv[i] * W1[i * DIM + o];
    hid[o] = acc;
    __syncthreads();
    if (o < ODIM) {
        float p = b2[o];
#pragma unroll 8
        for (int i = 0; i < DIM; ++i) p += hid[i] * W2[i * ODIM + o];
        pred[(size_t)gi * ODIM + o] = p;
    }
}

extern "C" void kernel_launch(void* const* d_in, const int* in_sizes, int n_in,
                              void* d_out, int out_size, void* d_ws, size_t ws_size,
                              hipStream_t stream) {
    const float* x    = (const float*)d_in[0];
    const int* eidx   = (const int*)d_in[1];
    const int* src    = eidx;
    const int* dst    = eidx + N_EDGES;
    const int* batch  = (const int*)d_in[2];
    const float* Wl1  = (const float*)d_in[4];
    const float* bl1  = (const float*)d_in[5];
    const float* Wr1  = (const float*)d_in[6];
    const float* Wl2  = (const float*)d_in[7];
    const float* bl2  = (const float*)d_in[8];
    const float* Wr2  = (const float*)d_in[9];
    const float* W1   = (const float*)d_in[10];
    const float* b1   = (const float*)d_in[11];
    const float* W2   = (const float*)d_in[12];
    const float* b2   = (const float*)d_in[13];

    float* emb  = (float*)d_out;                          // [N_NODES, 64]
    float* pred = (float*)d_out + (size_t)N_NODES * DIM;  // [N_GRAPHS, 32]

    // Workspace layout
    int*   deg    = (int*)d_ws;                 // [N]
    int*   rowptr = deg + N_NODES;              // [N+1]
    int*   cursor = rowptr + N_NODES + 1;       // [N]
    int*   csr    = cursor + N_NODES;           // [E]
    int*   grow   = csr + N_EDGES;              // [G+1]
    float* hrelu  = (float*)(grow + N_GRAPHS + 1);       // [N,64]
    float* g      = hrelu + (size_t)N_NODES * DIM;       // [G,64]

    hipMemsetAsync(deg, 0, (size_t)N_NODES * sizeof(int), stream);

    deg_hist_kernel<<<(N_EDGES + 255) / 256, 256, 0, stream>>>(dst, deg);
    scan_kernel<<<1, 1024, 0, stream>>>(deg, rowptr, cursor, N_NODES);
    fill_csr_kernel<<<(N_EDGES + 255) / 256, 256, 0, stream>>>(src, dst, cursor, csr);
    graph_bounds_kernel<<<(N_GRAPHS + 1 + 255) / 256, 256, 0, stream>>>(batch, grow);

    // conv1: gather + matvec + relu -> hrelu
    conv4_kernel<1><<<N_NODES / 16, 256, 0, stream>>>(x, rowptr, csr, Wl1, bl1, Wr1, hrelu);
    // conv2: gather + matvec -> emb (pre-activation output)
    conv4_kernel<0><<<N_NODES / 16, 256, 0, stream>>>(hrelu, rowptr, csr, Wl2, bl2, Wr2, emb);
    // pool relu(emb) per graph
    pool_kernel<<<N_GRAPHS, 256, 0, stream>>>(emb, grow, g);
    // head
    head_kernel<<<N_GRAPHS, DIM, 0, stream>>>(g, W1, b1, W2, b2, pred);
}

// Round 4
// 405.091 us; speedup vs baseline: 6.1350x; 1.5212x over previous
//
#include <hip/hip_runtime.h>

constexpr int N_NODES  = 100000;
constexpr int N_EDGES  = 1200000;
constexpr int N_GRAPHS = 1000;
constexpr int DIM      = 64;
constexpr int ODIM     = 32;
constexpr int MAXD     = 10;

constexpr int SCAN_CHUNK = 1024;                       // elements per block
constexpr int SCAN_NB    = (N_NODES + SCAN_CHUNK - 1) / SCAN_CHUNK;  // 98

// ---------------------------------------------------------------------------
// CSR build step 1: in-degree histogram
// ---------------------------------------------------------------------------
__global__ void deg_hist_kernel(const int* __restrict__ dst, int* __restrict__ deg) {
    int e = blockIdx.x * blockDim.x + threadIdx.x;
    if (e < N_EDGES) atomicAdd(&deg[dst[e]], 1);
}

// ---------------------------------------------------------------------------
// Hierarchical exclusive scan, phase 1: per-block partial sums (1024 elems/block)
// ---------------------------------------------------------------------------
__global__ void scan_partial_kernel(const int* __restrict__ deg, int* __restrict__ partials) {
    __shared__ int red[256];
    int b = blockIdx.x, t = threadIdx.x;
    int base = b * SCAN_CHUNK + t * 4;
    int s = 0;
    if (base < N_NODES) {   // N_NODES % 4 == 0, so full int4 whenever in range
        int4 v = *reinterpret_cast<const int4*>(deg + base);
        s = v.x + v.y + v.z + v.w;
    }
    red[t] = s;
    __syncthreads();
    for (int off = 128; off > 0; off >>= 1) {
        if (t < off) red[t] += red[t + off];
        __syncthreads();
    }
    if (t == 0) partials[b] = red[0];
}

// ---------------------------------------------------------------------------
// Phase 2: single small block scans the 98 partials -> block offsets; writes total
// ---------------------------------------------------------------------------
__global__ void scan_partials_kernel(const int* __restrict__ partials,
                                     int* __restrict__ blockoff,
                                     int* __restrict__ rowptr) {
    __shared__ int sh[128];
    int t = threadIdx.x;
    int v = (t < SCAN_NB) ? partials[t] : 0;
    sh[t] = v;
    __syncthreads();
    for (int off = 1; off < 128; off <<= 1) {
        int u = (t >= off) ? sh[t - off] : 0;
        __syncthreads();
        sh[t] += u;
        __syncthreads();
    }
    if (t < SCAN_NB) blockoff[t] = sh[t] - v;   // exclusive
    if (t == SCAN_NB - 1) rowptr[N_NODES] = sh[t];
}

// ---------------------------------------------------------------------------
// Phase 3: per-block exclusive scan + block offset -> rowptr & cursor
// ---------------------------------------------------------------------------
__global__ void scan_final_kernel(const int* __restrict__ deg,
                                  const int* __restrict__ blockoff,
                                  int* __restrict__ rowptr,
                                  int* __restrict__ cursor) {
    __shared__ int sh[256];
    int b = blockIdx.x, t = threadIdx.x;
    int base = b * SCAN_CHUNK + t * 4;
    int4 v = make_int4(0, 0, 0, 0);
    if (base < N_NODES) v = *reinterpret_cast<const int4*>(deg + base);
    int s = v.x + v.y + v.z + v.w;
    sh[t] = s;
    __syncthreads();
    for (int off = 1; off < 256; off <<= 1) {
        int u = (t >= off) ? sh[t - off] : 0;
        __syncthreads();
        sh[t] += u;
        __syncthreads();
    }
    if (base < N_NODES) {
        int p0 = sh[t] - s + blockoff[b];
        int p1 = p0 + v.x, p2 = p1 + v.y, p3 = p2 + v.z;
        int4 pr = make_int4(p0, p1, p2, p3);
        *reinterpret_cast<int4*>(rowptr + base) = pr;
        *reinterpret_cast<int4*>(cursor + base) = pr;
    }
}

// ---------------------------------------------------------------------------
// CSR build step 3: bin edges; csr[pos] = src node id
// ---------------------------------------------------------------------------
__global__ void fill_csr_kernel(const int* __restrict__ src, const int* __restrict__ dst,
                                int* __restrict__ cursor, int* __restrict__ csr) {
    int e = blockIdx.x * blockDim.x + threadIdx.x;
    if (e < N_EDGES) {
        int p = atomicAdd(&cursor[dst[e]], 1);
        csr[p] = src[e];
    }
}

// ---------------------------------------------------------------------------
// Graph node ranges via binary search on sorted batch
// ---------------------------------------------------------------------------
__global__ void graph_bounds_kernel(const int* __restrict__ batch, int* __restrict__ grow) {
    int t = blockIdx.x * blockDim.x + threadIdx.x;
    if (t > N_GRAPHS) return;
    if (t == N_GRAPHS) { grow[t] = N_NODES; return; }
    int lo = 0, hi = N_NODES;
    while (lo < hi) { int mid = (lo + hi) >> 1; if (batch[mid] < t) lo = mid + 1; else hi = mid; }
    grow[t] = lo;
}

// ---------------------------------------------------------------------------
// Fused gather + MFConv, 16 lanes per node (float4 per lane), 4 nodes/wave.
// ---------------------------------------------------------------------------
template <int RELU>
__global__ void conv4_kernel(const float* __restrict__ xin,
                             const int* __restrict__ rowptr,
                             const int* __restrict__ csr,
                             const float* __restrict__ Wl,
                             const float* __restrict__ bl,
                             const float* __restrict__ Wr,
                             float* __restrict__ out) {
    __shared__ float lds_h[16][DIM];
    __shared__ float lds_x[16][DIM];
    int grp = threadIdx.x >> 4;
    int q   = threadIdx.x & 15;
    int node = blockIdx.x * 16 + grp;   // grid = N/16 exactly

    int beg = rowptr[node];
    int end = rowptr[node + 1];

    float4 xv = *reinterpret_cast<const float4*>(xin + (size_t)node * DIM + q * 4);
    float4 hs = make_float4(0.f, 0.f, 0.f, 0.f);

    int e = beg;
    for (; e + 8 <= end; e += 8) {
        int s0 = csr[e + 0], s1 = csr[e + 1], s2 = csr[e + 2], s3 = csr[e + 3];
        int s4 = csr[e + 4], s5 = csr[e + 5], s6 = csr[e + 6], s7 = csr[e + 7];
        float4 a = *reinterpret_cast<const float4*>(xin + (size_t)s0 * DIM + q * 4);
        float4 b = *reinterpret_cast<const float4*>(xin + (size_t)s1 * DIM + q * 4);
        float4 c = *reinterpret_cast<const float4*>(xin + (size_t)s2 * DIM + q * 4);
        float4 d = *reinterpret_cast<const float4*>(xin + (size_t)s3 * DIM + q * 4);
        float4 f = *reinterpret_cast<const float4*>(xin + (size_t)s4 * DIM + q * 4);
        float4 g = *reinterpret_cast<const float4*>(xin + (size_t)s5 * DIM + q * 4);
        float4 h = *reinterpret_cast<const float4*>(xin + (size_t)s6 * DIM + q * 4);
        float4 k = *reinterpret_cast<const float4*>(xin + (size_t)s7 * DIM + q * 4);
        hs.x += (a.x + b.x) + (c.x + d.x) + (f.x + g.x) + (h.x + k.x);
        hs.y += (a.y + b.y) + (c.y + d.y) + (f.y + g.y) + (h.y + k.y);
        hs.z += (a.z + b.z) + (c.z + d.z) + (f.z + g.z) + (h.z + k.z);
        hs.w += (a.w + b.w) + (c.w + d.w) + (f.w + g.w) + (h.w + k.w);
    }
    for (; e + 4 <= end; e += 4) {
        int s0 = csr[e + 0], s1 = csr[e + 1], s2 = csr[e + 2], s3 = csr[e + 3];
        float4 a = *reinterpret_cast<const float4*>(xin + (size_t)s0 * DIM + q * 4);
        float4 b = *reinterpret_cast<const float4*>(xin + (size_t)s1 * DIM + q * 4);
        float4 c = *reinterpret_cast<const float4*>(xin + (size_t)s2 * DIM + q * 4);
        float4 d = *reinterpret_cast<const float4*>(xin + (size_t)s3 * DIM + q * 4);
        hs.x += (a.x + b.x) + (c.x + d.x);
        hs.y += (a.y + b.y) + (c.y + d.y);
        hs.z += (a.z + b.z) + (c.z + d.z);
        hs.w += (a.w + b.w) + (c.w + d.w);
    }
    for (; e < end; ++e) {
        int s = csr[e];
        float4 a = *reinterpret_cast<const float4*>(xin + (size_t)s * DIM + q * 4);
        hs.x += a.x; hs.y += a.y; hs.z += a.z; hs.w += a.w;
    }

    lds_h[grp][q * 4 + 0] = hs.x;
    lds_h[grp][q * 4 + 1] = hs.y;
    lds_h[grp][q * 4 + 2] = hs.z;
    lds_h[grp][q * 4 + 3] = hs.w;
    lds_x[grp][q * 4 + 0] = xv.x;
    lds_x[grp][q * 4 + 1] = xv.y;
    lds_x[grp][q * 4 + 2] = xv.z;
    lds_x[grp][q * 4 + 3] = xv.w;
    __syncthreads();

    int d = end - beg;
    d = d > MAXD ? MAXD : d;
    const float* wl = Wl + (size_t)d * DIM * DIM + q * 4;
    const float* wr = Wr + (size_t)d * DIM * DIM + q * 4;
    float4 acc = *reinterpret_cast<const float4*>(bl + d * DIM + q * 4);

#pragma unroll 8
    for (int i = 0; i < DIM; ++i) {
        float h  = lds_h[grp][i];
        float xx = lds_x[grp][i];
        float4 wlv = *reinterpret_cast<const float4*>(wl + i * DIM);
        float4 wrv = *reinterpret_cast<const float4*>(wr + i * DIM);
        acc.x += h * wlv.x + xx * wrv.x;
        acc.y += h * wlv.y + xx * wrv.y;
        acc.z += h * wlv.z + xx * wrv.z;
        acc.w += h * wlv.w + xx * wrv.w;
    }
    if (RELU) {
        acc.x = fmaxf(acc.x, 0.f); acc.y = fmaxf(acc.y, 0.f);
        acc.z = fmaxf(acc.z, 0.f); acc.w = fmaxf(acc.w, 0.f);
    }
    *reinterpret_cast<float4*>(out + (size_t)node * DIM + q * 4) = acc;
}

// ---------------------------------------------------------------------------
// global_add_pool of relu(emb): one block per graph, contiguous node range
// ---------------------------------------------------------------------------
__global__ void pool_kernel(const float* __restrict__ emb,
                            const int* __restrict__ grow,
                            float* __restrict__ g) {
    __shared__ float red[4][DIM];
    int gi = blockIdx.x;
    int w = threadIdx.x >> 6;
    int lane = threadIdx.x & 63;
    int beg = grow[gi], end = grow[gi + 1];
    float acc = 0.f;
    for (int n = beg + w; n < end; n += 4)
        acc += fmaxf(emb[(size_t)n * DIM + lane], 0.f);
    red[w][lane] = acc;
    __syncthreads();
    if (w == 0) {
        g[(size_t)gi * DIM + lane] = red[0][lane] + red[1][lane] + red[2][lane] + red[3][lane];
    }
}

// ---------------------------------------------------------------------------
// Head: hid = g@W1 + b1 ; pred = hid@W2 + b2 (one 64-thread block per graph)
// ---------------------------------------------------------------------------
__global__ void head_kernel(const float* __restrict__ g,
                            const float* __restrict__ W1,
                            const float* __restrict__ b1,
                            const float* __restrict__ W2,
                            const float* __restrict__ b2,
                            float* __restrict__ pred) {
    __shared__ float hid[DIM];
    int gi = blockIdx.x;
    int o = threadIdx.x;
    const float* gv = g + (size_t)gi * DIM;
    float acc = b1[o];
#pragma unroll 8
    for (int i = 0; i < DIM; ++i) acc += gv[i] * W1[i * DIM + o];
    hid[o] = acc;
    __syncthreads();
    if (o < ODIM) {
        float p = b2[o];
#pragma unroll 8
        for (int i = 0; i < DIM; ++i) p += hid[i] * W2[i * ODIM + o];
        pred[(size_t)gi * ODIM + o] = p;
    }
}

extern "C" void kernel_launch(void* const* d_in, const int* in_sizes, int n_in,
                              void* d_out, int out_size, void* d_ws, size_t ws_size,
                              hipStream_t stream) {
    const float* x    = (const float*)d_in[0];
    const int* eidx   = (const int*)d_in[1];
    const int* src    = eidx;
    const int* dst    = eidx + N_EDGES;
    const int* batch  = (const int*)d_in[2];
    const float* Wl1  = (const float*)d_in[4];
    const float* bl1  = (const float*)d_in[5];
    const float* Wr1  = (const float*)d_in[6];
    const float* Wl2  = (const float*)d_in[7];
    const float* bl2  = (const float*)d_in[8];
    const float* Wr2  = (const float*)d_in[9];
    const float* W1   = (const float*)d_in[10];
    const float* b1   = (const float*)d_in[11];
    const float* W2   = (const float*)d_in[12];
    const float* b2   = (const float*)d_in[13];

    float* emb  = (float*)d_out;                          // [N_NODES, 64]
    float* pred = (float*)d_out + (size_t)N_NODES * DIM;  // [N_GRAPHS, 32]

    // Workspace layout
    int*   deg      = (int*)d_ws;                // [N]      (16B aligned)
    int*   rowptr   = deg + N_NODES;             // [N+1]
    int*   cursor   = rowptr + N_NODES + 4;      // [N]      (keep 16B alignment)
    int*   csr      = cursor + N_NODES;          // [E]
    int*   grow     = csr + N_EDGES;             // [G+1]
    int*   partials = grow + N_GRAPHS + 1;       // [SCAN_NB]
    int*   blockoff = partials + SCAN_NB;        // [SCAN_NB]
    float* hrelu    = (float*)(blockoff + SCAN_NB + 2);  // [N,64]
    float* g        = hrelu + (size_t)N_NODES * DIM;     // [G,64]

    hipMemsetAsync(deg, 0, (size_t)N_NODES * sizeof(int), stream);

    deg_hist_kernel<<<(N_EDGES + 255) / 256, 256, 0, stream>>>(dst, deg);
    scan_partial_kernel<<<SCAN_NB, 256, 0, stream>>>(deg, partials);
    scan_partials_kernel<<<1, 128, 0, stream>>>(partials, blockoff, rowptr);
    scan_final_kernel<<<SCAN_NB, 256, 0, stream>>>(deg, blockoff, rowptr, cursor);
    fill_csr_kernel<<<(N_EDGES + 255) / 256, 256, 0, stream>>>(src, dst, cursor, csr);
    graph_bounds_kernel<<<(N_GRAPHS + 1 + 255) / 256, 256, 0, stream>>>(batch, grow);

    // conv1: gather + matvec + relu -> hrelu
    conv4_kernel<1><<<N_NODES / 16, 256, 0, stream>>>(x, rowptr, csr, Wl1, bl1, Wr1, hrelu);
    // conv2: gather + matvec -> emb (pre-activation output)
    conv4_kernel<0><<<N_NODES / 16, 256, 0, stream>>>(hrelu, rowptr, csr, Wl2, bl2, Wr2, emb);
    // pool relu(emb) per graph
    pool_kernel<<<N_GRAPHS, 256, 0, stream>>>(emb, grow, g);
    // head
    head_kernel<<<N_GRAPHS, DIM, 0, stream>>>(g, W1, b1, W2, b2, pred);
}